// Round 1
// baseline (313.726 us; speedup 1.0000x reference)
//
#include <hip/hip_runtime.h>
#include <hip/hip_bf16.h>
#include <cstdint>

// Problem dims
#define Bn 8
#define Cn 256
#define Hn 48
#define GRID_N 3
#define NUM_MEM 9
#define WSZ 16
#define Sn 128
#define Dn 65536   // 16*16*256
#define KTOP 5

// ---------------- Phase A: x (B,C,H,W) -> q (B,M,D), D = (i*16+j)*256 + c ----
__global__ __launch_bounds__(256) void k_x2q(const float* __restrict__ x,
                                             float* __restrict__ q) {
    const int h = blockIdx.x;          // 0..47
    const int b = blockIdx.y;          // 0..7
    const int gh = h >> 4, i = h & 15;
    __shared__ float tile[Cn * Hn];    // [c][w], 48KB
    const float* xp = x + (size_t)b * Cn * Hn * Hn + (size_t)h * Hn;
    for (int o = threadIdx.x; o < Cn * Hn; o += blockDim.x) {
        int c = o / Hn, w = o - c * Hn;
        tile[o] = xp[(size_t)c * Hn * Hn + w];
    }
    __syncthreads();
    for (int gw = 0; gw < 3; ++gw) {
        float* qp = q + (size_t)(b * NUM_MEM + gh * 3 + gw) * Dn + i * (WSZ * Cn);
        for (int l = threadIdx.x; l < WSZ * Cn; l += blockDim.x) {
            int j = l >> 8, c = l & 255;
            qp[l] = tile[c * Hn + gw * WSZ + j];
        }
    }
}

// ---------------- Phase B: att[e,b,m,s] = q[b,m,:] . mem_e[m,s,:] ------------
#define SB 2   // s-rows per block
__global__ __launch_bounds__(256) void k_att(const float* __restrict__ q,
                                             const float* __restrict__ mem1,
                                             const float* __restrict__ mem2,
                                             float* __restrict__ att) {
    const int sblk = blockIdx.x;       // 0..63
    const int m    = blockIdx.y;       // 0..8
    const int e    = blockIdx.z;       // 0..1
    const float* mem = e ? mem2 : mem1;
    const float* mp = mem + ((size_t)m * Sn + sblk * SB) * Dn;

    float acc[Bn][SB];
#pragma unroll
    for (int b = 0; b < Bn; ++b)
#pragma unroll
        for (int r = 0; r < SB; ++r) acc[b][r] = 0.f;

    for (int d = threadIdx.x * 4; d < Dn; d += 1024) {
        float4 M[SB];
#pragma unroll
        for (int r = 0; r < SB; ++r)
            M[r] = *(const float4*)(mp + (size_t)r * Dn + d);
#pragma unroll
        for (int b = 0; b < Bn; ++b) {
            float4 Q = *(const float4*)(q + (size_t)(b * NUM_MEM + m) * Dn + d);
#pragma unroll
            for (int r = 0; r < SB; ++r) {
                acc[b][r] += Q.x * M[r].x + Q.y * M[r].y + Q.z * M[r].z + Q.w * M[r].w;
            }
        }
    }

    // wave-level reduce, then cross-wave via LDS
    __shared__ float red[4][Bn][SB];
    const int lane = threadIdx.x & 63, wave = threadIdx.x >> 6;
#pragma unroll
    for (int b = 0; b < Bn; ++b)
#pragma unroll
        for (int r = 0; r < SB; ++r) {
            float v = acc[b][r];
#pragma unroll
            for (int off = 32; off > 0; off >>= 1) v += __shfl_down(v, off);
            if (lane == 0) red[wave][b][r] = v;
        }
    __syncthreads();
    if (threadIdx.x < Bn * SB) {
        int b = threadIdx.x / SB, r = threadIdx.x % SB;
        float v = red[0][b][r] + red[1][b][r] + red[2][b][r] + red[3][b][r];
        att[((size_t)(e * Bn + b) * NUM_MEM + m) * Sn + sblk * SB + r] = v;
    }
}

// ---------------- Phase C: softmax + top-5 threshold + hard-shrink + L1 -----
__global__ __launch_bounds__(128) void k_smax(const float* __restrict__ att,
                                              float* __restrict__ w) {
    const int row = blockIdx.x;        // 0..143  = (e*8+b)*9+m
    const int t = threadIdx.x;         // 0..127
    __shared__ float sf[Sn];
    __shared__ unsigned long long sk[Sn];

    float v = att[(size_t)row * Sn + t];
    sf[t] = v; __syncthreads();
    for (int s = 64; s > 0; s >>= 1) { if (t < s) sf[t] = fmaxf(sf[t], sf[t + s]); __syncthreads(); }
    float mx = sf[0]; __syncthreads();

    float e = expf(v - mx);
    sf[t] = e; __syncthreads();
    for (int s = 64; s > 0; s >>= 1) { if (t < s) sf[t] += sf[t + s]; __syncthreads(); }
    float sum = sf[0]; __syncthreads();
    float y = e / sum;                 // softmax (y > 0)

    // 5 iterations of packed (value,index) argmax-with-exclusion -> 5th largest
    bool alive = true;
    float thres = 0.f;
    unsigned int ybits = __float_as_uint(y);   // y>0 -> bits monotonic
    for (int it = 0; it < KTOP; ++it) {
        sk[t] = alive ? ((((unsigned long long)ybits) << 32) | (unsigned)t) : 0ull;
        __syncthreads();
        for (int s = 64; s > 0; s >>= 1) {
            if (t < s) { if (sk[t + s] > sk[t]) sk[t] = sk[t + s]; }
            __syncthreads();
        }
        unsigned long long kmax = sk[0];
        __syncthreads();
        if ((unsigned)(kmax & 0xffffffffull) == (unsigned)t) alive = false;
        thres = __uint_as_float((unsigned)(kmax >> 32));
    }

    float d   = y - thres;
    float num = fmaxf(d, 0.f) * y;
    float yh  = num / (fabsf(d) + 1e-12f);     // exact reference formula

    sf[t] = yh; __syncthreads();
    for (int s = 64; s > 0; s >>= 1) { if (t < s) sf[t] += sf[t + s]; __syncthreads(); }
    float l1 = sf[0];
    w[(size_t)row * Sn + t] = yh / fmaxf(l1, 1e-12f);
}

// ---------------- Phase D: acc[b,m,:] = sum_s w1*mem1 + w2*mem2 -------------
__global__ __launch_bounds__(256) void k_acc(const float* __restrict__ w,
                                             const float* __restrict__ mem1,
                                             const float* __restrict__ mem2,
                                             float* __restrict__ acc) {
    const int chunk = blockIdx.x;      // 0..15 (4096 floats each)
    const int m     = blockIdx.y;      // 0..8
    const int b     = blockIdx.z;      // 0..7
    __shared__ int   nz[2];
    __shared__ int   idx[2][16];
    __shared__ float wv[2][16];
    if (threadIdx.x < 2) nz[threadIdx.x] = 0;
    __syncthreads();
    {
        int eidx = threadIdx.x >> 7;           // 0 or 1
        int s    = threadIdx.x & 127;
        float ww = w[((size_t)(eidx * Bn + b) * NUM_MEM + m) * Sn + s];
        if (ww != 0.f) {
            int p = atomicAdd(&nz[eidx], 1);
            if (p < 16) { idx[eidx][p] = s; wv[eidx][p] = ww; }
        }
    }
    __syncthreads();
    const int n1 = nz[0], n2 = nz[1];
    const size_t mbase = (size_t)m * Sn * Dn;
    const int dbase = chunk * 4096;
    for (int l = threadIdx.x * 4; l < 4096; l += 1024) {
        int d = dbase + l;
        float4 a = {0.f, 0.f, 0.f, 0.f};
        for (int j = 0; j < n1; ++j) {
            const float4 r = *(const float4*)(mem1 + mbase + (size_t)idx[0][j] * Dn + d);
            float ww = wv[0][j];
            a.x += ww * r.x; a.y += ww * r.y; a.z += ww * r.z; a.w += ww * r.w;
        }
        for (int j = 0; j < n2; ++j) {
            const float4 r = *(const float4*)(mem2 + mbase + (size_t)idx[1][j] * Dn + d);
            float ww = wv[1][j];
            a.x += ww * r.x; a.y += ww * r.y; a.z += ww * r.z; a.w += ww * r.w;
        }
        *(float4*)(acc + (size_t)(b * NUM_MEM + m) * Dn + d) = a;
    }
}

// ---------------- Phase E: acc (B,M,D) -> out (B,C,H,W) ---------------------
__global__ __launch_bounds__(256) void k_q2x(const float* __restrict__ acc,
                                             float* __restrict__ out) {
    const int h = blockIdx.x;          // 0..47
    const int b = blockIdx.y;          // 0..7
    const int gh = h >> 4, i = h & 15;
    __shared__ float tile[Cn * Hn];    // [c][w]
    for (int gw = 0; gw < 3; ++gw) {
        const float* ap = acc + (size_t)(b * NUM_MEM + gh * 3 + gw) * Dn + i * (WSZ * Cn);
        for (int l = threadIdx.x; l < WSZ * Cn; l += blockDim.x) {
            int j = l >> 8, c = l & 255;
            tile[c * Hn + gw * WSZ + j] = ap[l];
        }
    }
    __syncthreads();
    float* op = out + (size_t)b * Cn * Hn * Hn + (size_t)h * Hn;
    for (int o = threadIdx.x; o < Cn * Hn; o += blockDim.x) {
        int c = o / Hn, wcol = o - c * Hn;
        op[(size_t)c * Hn * Hn + wcol] = tile[o];
    }
}

extern "C" void kernel_launch(void* const* d_in, const int* in_sizes, int n_in,
                              void* d_out, int out_size, void* d_ws, size_t ws_size,
                              hipStream_t stream) {
    const float* x    = (const float*)d_in[0];
    const float* mem1 = (const float*)d_in[1];
    const float* mem2 = (const float*)d_in[2];
    float* out = (float*)d_out;

    // workspace layout (floats): q/acc [B*M*D], att [2*B*M*S], w [2*B*M*S]
    float* q   = (float*)d_ws;                      // 4,718,592 fl (aliased as acc later)
    float* att = q + (size_t)Bn * NUM_MEM * Dn;     // 18,432 fl
    float* wbuf = att + 2 * Bn * NUM_MEM * Sn;      // 18,432 fl

    k_x2q<<<dim3(Hn, Bn), 256, 0, stream>>>(x, q);
    k_att<<<dim3(Sn / SB, NUM_MEM, 2), 256, 0, stream>>>(q, mem1, mem2, att);
    k_smax<<<2 * Bn * NUM_MEM, 128, 0, stream>>>(att, wbuf);
    k_acc<<<dim3(16, NUM_MEM, Bn), 256, 0, stream>>>(wbuf, mem1, mem2, q /*acc, aliases q*/);
    k_q2x<<<dim3(Hn, Bn), 256, 0, stream>>>(q, out);
}

// Round 2
// 233.855 us; speedup vs baseline: 1.3415x; 1.3415x over previous
//
#include <hip/hip_runtime.h>
#include <hip/hip_bf16.h>
#include <cstdint>

// Problem dims
#define Bn 8
#define Cn 256
#define Hn 48
#define NUM_MEM 9
#define WSZ 16
#define Sn 128
#define Dn 65536   // 16*16*256
#define KTOP 5
#define ND 128     // d-chunks for k_att
#define CH 512     // floats per chunk (= 64 lanes * 2 float4)

// ---------------- Phase A: x (B,C,H,W) -> q (B,M,D), D = (i*16+j)*256 + c ----
__global__ __launch_bounds__(256) void k_x2q(const float* __restrict__ x,
                                             float* __restrict__ q) {
    const int h = blockIdx.x;          // 0..47
    const int b = blockIdx.y;          // 0..7
    const int gh = h >> 4, i = h & 15;
    __shared__ float tile[Cn * Hn];    // [c][w], 48KB
    const float* xp = x + (size_t)b * Cn * Hn * Hn + (size_t)h * Hn;
    for (int o = threadIdx.x; o < Cn * Hn; o += blockDim.x) {
        int c = o / Hn, w = o - c * Hn;
        tile[o] = xp[(size_t)c * Hn * Hn + w];
    }
    __syncthreads();
    for (int gw = 0; gw < 3; ++gw) {
        float* qp = q + (size_t)(b * NUM_MEM + gh * 3 + gw) * Dn + i * (WSZ * Cn);
        for (int l = threadIdx.x; l < WSZ * Cn; l += blockDim.x) {
            int j = l >> 8, c = l & 255;
            qp[l] = tile[c * Hn + gw * WSZ + j];
        }
    }
}

// ---------------- Phase B: partial dots, q register-cached ------------------
// block = (dc, m, e); wave handles s = wave, wave+4, ... (32 rows)
// ap[dc][(e*8+b)*9+m][s] = partial dot over chunk dc
__global__ __launch_bounds__(256) void k_att2(const float* __restrict__ q,
                                              const float* __restrict__ mem1,
                                              const float* __restrict__ mem2,
                                              float* __restrict__ ap) {
    const int dc = blockIdx.x;   // 0..ND-1
    const int mw = blockIdx.y;   // 0..8
    const int e  = blockIdx.z;   // 0..1
    const float4* mem4 = (const float4*)(e ? mem2 : mem1);
    const float4* q4   = (const float4*)q;
    const int lane = threadIdx.x & 63, wave = threadIdx.x >> 6;

    // register-cache the q chunk: 8 batches x 2 float4 (lane covers full chunk)
    float4 qr[8][2];
#pragma unroll
    for (int b = 0; b < 8; ++b) {
        const size_t qb = (size_t)(b * NUM_MEM + mw) * (Dn / 4) + (size_t)dc * (CH / 4);
        qr[b][0] = q4[qb + lane];
        qr[b][1] = q4[qb + 64 + lane];
    }

    const float4* mrow = mem4 + (size_t)(mw * Sn + wave) * (Dn / 4) + (size_t)dc * (CH / 4) + lane;
    float4 Mv0 = mrow[0], Mv1 = mrow[64];

    for (int s = wave; s < Sn; s += 4) {
        // prefetch next s-row (clamped on last iteration; uniform branch)
        const float4* nrow = (s + 4 < Sn) ? (mrow + Dn) : mrow;   // Dn float4 = 4 rows
        float4 Mn0 = nrow[0], Mn1 = nrow[64];

        float a[8];
#pragma unroll
        for (int b = 0; b < 8; ++b) {
            a[b] = qr[b][0].x * Mv0.x + qr[b][0].y * Mv0.y + qr[b][0].z * Mv0.z + qr[b][0].w * Mv0.w
                 + qr[b][1].x * Mv1.x + qr[b][1].y * Mv1.y + qr[b][1].z * Mv1.z + qr[b][1].w * Mv1.w;
        }

        // fold-reduce: 8 values across 64 lanes in ~10 cross-lane ops.
        // After 3 merge steps lane l holds partial of value (l&7) over its 8-lane group.
#pragma unroll
        for (int i = 0; i < 3; ++i) {
            const int mk = 1 << i;
            const bool up = (lane & mk) != 0;
#pragma unroll
            for (int j = 0; j < (8 >> (i + 1)); ++j) {
                float lo = a[2 * j], hi = a[2 * j + 1];
                float mine = up ? hi : lo;
                float th   = __shfl_xor(up ? lo : hi, mk, 64);
                a[j] = mine + th;
            }
        }
        float r = a[0];
#pragma unroll
        for (int off = 8; off < 64; off <<= 1) r += __shfl_xor(r, off, 64);
        if (lane < 8)   // lane b holds S_b
            ap[((size_t)dc * 144 + (size_t)(e * 8 + lane) * 9 + mw) * Sn + s] = r;

        Mv0 = Mn0; Mv1 = Mn1;
        mrow += Dn;
    }
}

// ---------------- Phase C: nd-reduce + softmax + top-5 + shrink + L1 --------
__global__ __launch_bounds__(128) void k_smax(const float* __restrict__ ap,
                                              float* __restrict__ w) {
    const int row = blockIdx.x;        // 0..143  = (e*8+b)*9+m
    const int t = threadIdx.x;         // 0..127
    __shared__ float sf[Sn];
    __shared__ unsigned long long sk[Sn];

    float v = 0.f;
#pragma unroll 8
    for (int nd = 0; nd < ND; ++nd)
        v += ap[((size_t)nd * 144 + row) * Sn + t];

    sf[t] = v; __syncthreads();
    for (int s = 64; s > 0; s >>= 1) { if (t < s) sf[t] = fmaxf(sf[t], sf[t + s]); __syncthreads(); }
    float mx = sf[0]; __syncthreads();

    float e = expf(v - mx);
    sf[t] = e; __syncthreads();
    for (int s = 64; s > 0; s >>= 1) { if (t < s) sf[t] += sf[t + s]; __syncthreads(); }
    float sum = sf[0]; __syncthreads();
    float y = e / sum;                 // softmax (y > 0)

    // 5 iterations of packed (value,index) argmax-with-exclusion -> 5th largest
    bool alive = true;
    float thres = 0.f;
    unsigned int ybits = __float_as_uint(y);   // y>0 -> bits monotonic
    for (int it = 0; it < KTOP; ++it) {
        sk[t] = alive ? ((((unsigned long long)ybits) << 32) | (unsigned)t) : 0ull;
        __syncthreads();
        for (int s = 64; s > 0; s >>= 1) {
            if (t < s) { if (sk[t + s] > sk[t]) sk[t] = sk[t + s]; }
            __syncthreads();
        }
        unsigned long long kmax = sk[0];
        __syncthreads();
        if ((unsigned)(kmax & 0xffffffffull) == (unsigned)t) alive = false;
        thres = __uint_as_float((unsigned)(kmax >> 32));
    }

    float d   = y - thres;
    float num = fmaxf(d, 0.f) * y;
    float yh  = num / (fabsf(d) + 1e-12f);     // exact reference formula

    sf[t] = yh; __syncthreads();
    for (int s = 64; s > 0; s >>= 1) { if (t < s) sf[t] += sf[t + s]; __syncthreads(); }
    float l1 = sf[0];
    w[(size_t)row * Sn + t] = yh / fmaxf(l1, 1e-12f);
}

// ---------------- Phase D: acc[b,m,:] = sum_s w1*mem1 + w2*mem2 -------------
__global__ __launch_bounds__(256) void k_acc(const float* __restrict__ w,
                                             const float* __restrict__ mem1,
                                             const float* __restrict__ mem2,
                                             float* __restrict__ acc) {
    const int chunk = blockIdx.x;      // 0..15 (4096 floats each)
    const int m     = blockIdx.y;      // 0..8
    const int b     = blockIdx.z;      // 0..7
    __shared__ int   nz[2];
    __shared__ int   idx[2][16];
    __shared__ float wv[2][16];
    if (threadIdx.x < 2) nz[threadIdx.x] = 0;
    __syncthreads();
    {
        int eidx = threadIdx.x >> 7;           // 0 or 1
        int s    = threadIdx.x & 127;
        float ww = w[((size_t)(eidx * Bn + b) * NUM_MEM + m) * Sn + s];
        if (ww != 0.f) {
            int p = atomicAdd(&nz[eidx], 1);
            if (p < 16) { idx[eidx][p] = s; wv[eidx][p] = ww; }
        }
    }
    __syncthreads();
    const int n1 = nz[0], n2 = nz[1];
    const size_t mbase = (size_t)m * Sn * Dn;
    const int dbase = chunk * 4096;
    for (int l = threadIdx.x * 4; l < 4096; l += 1024) {
        int d = dbase + l;
        float4 a = {0.f, 0.f, 0.f, 0.f};
        for (int j = 0; j < n1; ++j) {
            const float4 r = *(const float4*)(mem1 + mbase + (size_t)idx[0][j] * Dn + d);
            float ww = wv[0][j];
            a.x += ww * r.x; a.y += ww * r.y; a.z += ww * r.z; a.w += ww * r.w;
        }
        for (int j = 0; j < n2; ++j) {
            const float4 r = *(const float4*)(mem2 + mbase + (size_t)idx[1][j] * Dn + d);
            float ww = wv[1][j];
            a.x += ww * r.x; a.y += ww * r.y; a.z += ww * r.z; a.w += ww * r.w;
        }
        *(float4*)(acc + (size_t)(b * NUM_MEM + m) * Dn + d) = a;
    }
}

// ---------------- Phase E: acc (B,M,D) -> out (B,C,H,W) ---------------------
__global__ __launch_bounds__(256) void k_q2x(const float* __restrict__ acc,
                                             float* __restrict__ out) {
    const int h = blockIdx.x;          // 0..47
    const int b = blockIdx.y;          // 0..7
    const int gh = h >> 4, i = h & 15;
    __shared__ float tile[Cn * Hn];    // [c][w]
    for (int gw = 0; gw < 3; ++gw) {
        const float* ap = acc + (size_t)(b * NUM_MEM + gh * 3 + gw) * Dn + i * (WSZ * Cn);
        for (int l = threadIdx.x; l < WSZ * Cn; l += blockDim.x) {
            int j = l >> 8, c = l & 255;
            tile[c * Hn + gw * WSZ + j] = ap[l];
        }
    }
    __syncthreads();
    float* op = out + (size_t)b * Cn * Hn * Hn + (size_t)h * Hn;
    for (int o = threadIdx.x; o < Cn * Hn; o += blockDim.x) {
        int c = o / Hn, wcol = o - c * Hn;
        op[(size_t)c * Hn * Hn + wcol] = tile[o];
    }
}

extern "C" void kernel_launch(void* const* d_in, const int* in_sizes, int n_in,
                              void* d_out, int out_size, void* d_ws, size_t ws_size,
                              hipStream_t stream) {
    const float* x    = (const float*)d_in[0];
    const float* mem1 = (const float*)d_in[1];
    const float* mem2 = (const float*)d_in[2];
    float* out = (float*)d_out;

    // workspace: q/acc [B*M*D floats], w [2*B*M*S floats]
    float* q    = (float*)d_ws;
    float* wbuf = q + (size_t)Bn * NUM_MEM * Dn;
    // att partials live in d_out (9.4 MB of its 18.9 MB) — k_q2x overwrites it all later
    float* ap   = (float*)d_out;

    k_x2q<<<dim3(Hn, Bn), 256, 0, stream>>>(x, q);
    k_att2<<<dim3(ND, NUM_MEM, 2), 256, 0, stream>>>(q, mem1, mem2, ap);
    k_smax<<<2 * Bn * NUM_MEM, 128, 0, stream>>>(ap, wbuf);
    k_acc<<<dim3(16, NUM_MEM, Bn), 256, 0, stream>>>(wbuf, mem1, mem2, q /*acc*/);
    k_q2x<<<dim3(Hn, Bn), 256, 0, stream>>>(q, out);
}

// Round 3
// 233.655 us; speedup vs baseline: 1.3427x; 1.0009x over previous
//
#include <hip/hip_runtime.h>
#include <hip/hip_bf16.h>
#include <cstdint>

// Problem dims
#define Bn 8
#define Cn 256
#define Hn 48
#define NUM_MEM 9
#define WSZ 16
#define Sn 128
#define Dn 65536   // 16*16*256
#define KTOP 5
#define ND2 16     // d-segments for k_att3 (4096 floats each)

// ---------------- Phase A: x (B,C,H,W) -> q (B,M,D), D = (i*16+j)*256 + c ----
__global__ __launch_bounds__(256) void k_x2q(const float* __restrict__ x,
                                             float* __restrict__ q) {
    const int h = blockIdx.x;          // 0..47
    const int b = blockIdx.y;          // 0..7
    const int gh = h >> 4, i = h & 15;
    __shared__ float tile[Cn * Hn];    // [c][w], 48KB
    const float* xp = x + (size_t)b * Cn * Hn * Hn + (size_t)h * Hn;
    for (int o = threadIdx.x; o < Cn * Hn; o += blockDim.x) {
        int c = o / Hn, w = o - c * Hn;
        tile[o] = xp[(size_t)c * Hn * Hn + w];
    }
    __syncthreads();
    for (int gw = 0; gw < 3; ++gw) {
        float* qp = q + (size_t)(b * NUM_MEM + gh * 3 + gw) * Dn + i * (WSZ * Cn);
        for (int l = threadIdx.x; l < WSZ * Cn; l += blockDim.x) {
            int j = l >> 8, c = l & 255;
            qp[l] = tile[c * Hn + gw * WSZ + j];
        }
    }
}

// ---------------- Phase B: partial dots, persistent accumulators ------------
// block = (dseg, m, sgrp); rows R = sgrp*16 + wave*4 + r of the 256 (e,s) rows
// (e = sgrp>>3, s = (sgrp&7)*16 + wave*4 + r).
// ap[dseg][(e*8+b)*9+m][s] = partial dot over d-range [dseg*4096, +4096)
__global__ __launch_bounds__(256) void k_att3(const float* __restrict__ q,
                                              const float* __restrict__ mem1,
                                              const float* __restrict__ mem2,
                                              float* __restrict__ ap) {
    const int dseg = blockIdx.x;   // 0..15
    const int mw   = blockIdx.y;   // 0..8
    const int sgrp = blockIdx.z;   // 0..15
    const int e    = sgrp >> 3;
    const int lane = threadIdx.x & 63, wave = threadIdx.x >> 6;
    const int s0   = (sgrp & 7) * 16 + wave * 4;     // first of 4 s-rows

    const float4* mem4 = (const float4*)(e ? mem2 : mem1);
    const float4* q4   = (const float4*)q;

    const int off0 = dseg * 1024 + lane;             // float4 offset of step 0
    const float4* mr[4];
    const float4* qr[8];
#pragma unroll
    for (int r = 0; r < 4; ++r)
        mr[r] = mem4 + (size_t)(mw * Sn + s0 + r) * (Dn / 4) + off0;
#pragma unroll
    for (int b = 0; b < 8; ++b)
        qr[b] = q4 + (size_t)(b * NUM_MEM + mw) * (Dn / 4) + off0;

    float a[32];                                     // a[r*8+b]
#pragma unroll
    for (int i = 0; i < 32; ++i) a[i] = 0.f;

    float4 M[4], Q[8];
#pragma unroll
    for (int r = 0; r < 4; ++r) M[r] = mr[r][0];
#pragma unroll
    for (int b = 0; b < 8; ++b) Q[b] = qr[b][0];

    for (int step = 0; step < 16; ++step) {
        // prefetch next step (clamped on last; uniform branch)
        const int noff = (step < 15 ? step + 1 : step) * 64;
        float4 Mn[4], Qn[8];
#pragma unroll
        for (int r = 0; r < 4; ++r) Mn[r] = mr[r][noff];
#pragma unroll
        for (int b = 0; b < 8; ++b) Qn[b] = qr[b][noff];

#pragma unroll
        for (int r = 0; r < 4; ++r)
#pragma unroll
            for (int b = 0; b < 8; ++b) {
                a[r * 8 + b] += M[r].x * Q[b].x + M[r].y * Q[b].y
                              + M[r].z * Q[b].z + M[r].w * Q[b].w;
            }
#pragma unroll
        for (int r = 0; r < 4; ++r) M[r] = Mn[r];
#pragma unroll
        for (int b = 0; b < 8; ++b) Q[b] = Qn[b];
    }

    // fold-reduce: 32 values across 64 lanes; value idx = lane&31 at the end
#pragma unroll
    for (int k = 0; k < 5; ++k) {
        const int mk = 1 << k;
        const bool up = (lane & mk) != 0;
#pragma unroll
        for (int j = 0; j < (32 >> (k + 1)); ++j) {
            float lo = a[2 * j], hi = a[2 * j + 1];
            float mine = up ? hi : lo;
            float oth  = __shfl_xor(up ? lo : hi, mk, 64);
            a[j] = mine + oth;
        }
    }
    float rsum = a[0] + __shfl_xor(a[0], 32, 64);
    if (lane < 32) {
        const int b = lane & 7, r = (lane >> 3) & 3;
        const int s = s0 + r;
        ap[((size_t)dseg * 144 + (size_t)(e * 8 + b) * 9 + mw) * Sn + s] = rsum;
    }
}

// ---------------- Phase C: nd-reduce + softmax + top-5 + shrink + L1 --------
__global__ __launch_bounds__(128) void k_smax(const float* __restrict__ ap,
                                              float* __restrict__ w) {
    const int row = blockIdx.x;        // 0..143  = (e*8+b)*9+m
    const int t = threadIdx.x;         // 0..127
    __shared__ float sf[Sn];
    __shared__ unsigned long long sk[Sn];

    float v = 0.f;
#pragma unroll
    for (int nd = 0; nd < ND2; ++nd)
        v += ap[((size_t)nd * 144 + row) * Sn + t];

    sf[t] = v; __syncthreads();
    for (int s = 64; s > 0; s >>= 1) { if (t < s) sf[t] = fmaxf(sf[t], sf[t + s]); __syncthreads(); }
    float mx = sf[0]; __syncthreads();

    float e = expf(v - mx);
    sf[t] = e; __syncthreads();
    for (int s = 64; s > 0; s >>= 1) { if (t < s) sf[t] += sf[t + s]; __syncthreads(); }
    float sum = sf[0]; __syncthreads();
    float y = e / sum;                 // softmax (y > 0)

    // 5 iterations of packed (value,index) argmax-with-exclusion -> 5th largest
    bool alive = true;
    float thres = 0.f;
    unsigned int ybits = __float_as_uint(y);   // y>0 -> bits monotonic
    for (int it = 0; it < KTOP; ++it) {
        sk[t] = alive ? ((((unsigned long long)ybits) << 32) | (unsigned)t) : 0ull;
        __syncthreads();
        for (int s = 64; s > 0; s >>= 1) {
            if (t < s) { if (sk[t + s] > sk[t]) sk[t] = sk[t + s]; }
            __syncthreads();
        }
        unsigned long long kmax = sk[0];
        __syncthreads();
        if ((unsigned)(kmax & 0xffffffffull) == (unsigned)t) alive = false;
        thres = __uint_as_float((unsigned)(kmax >> 32));
    }

    float d   = y - thres;
    float num = fmaxf(d, 0.f) * y;
    float yh  = num / (fabsf(d) + 1e-12f);     // exact reference formula

    sf[t] = yh; __syncthreads();
    for (int s = 64; s > 0; s >>= 1) { if (t < s) sf[t] += sf[t + s]; __syncthreads(); }
    float l1 = sf[0];
    w[(size_t)row * Sn + t] = yh / fmaxf(l1, 1e-12f);
}

// ---------------- Phase D: acc[b,m,:] = sum_s w1*mem1 + w2*mem2 -------------
__global__ __launch_bounds__(256) void k_acc(const float* __restrict__ w,
                                             const float* __restrict__ mem1,
                                             const float* __restrict__ mem2,
                                             float* __restrict__ acc) {
    const int chunk = blockIdx.x;      // 0..15 (4096 floats each)
    const int m     = blockIdx.y;      // 0..8
    const int b     = blockIdx.z;      // 0..7
    __shared__ int   nz[2];
    __shared__ int   idx[2][16];
    __shared__ float wv[2][16];
    if (threadIdx.x < 2) nz[threadIdx.x] = 0;
    __syncthreads();
    {
        int eidx = threadIdx.x >> 7;           // 0 or 1
        int s    = threadIdx.x & 127;
        float ww = w[((size_t)(eidx * Bn + b) * NUM_MEM + m) * Sn + s];
        if (ww != 0.f) {
            int p = atomicAdd(&nz[eidx], 1);
            if (p < 16) { idx[eidx][p] = s; wv[eidx][p] = ww; }
        }
    }
    __syncthreads();
    const int n1 = nz[0], n2 = nz[1];
    const size_t mbase = (size_t)m * Sn * Dn;
    const int dbase = chunk * 4096;
    for (int l = threadIdx.x * 4; l < 4096; l += 1024) {
        int d = dbase + l;
        float4 a = {0.f, 0.f, 0.f, 0.f};
        for (int j = 0; j < n1; ++j) {
            const float4 r = *(const float4*)(mem1 + mbase + (size_t)idx[0][j] * Dn + d);
            float ww = wv[0][j];
            a.x += ww * r.x; a.y += ww * r.y; a.z += ww * r.z; a.w += ww * r.w;
        }
        for (int j = 0; j < n2; ++j) {
            const float4 r = *(const float4*)(mem2 + mbase + (size_t)idx[1][j] * Dn + d);
            float ww = wv[1][j];
            a.x += ww * r.x; a.y += ww * r.y; a.z += ww * r.z; a.w += ww * r.w;
        }
        *(float4*)(acc + (size_t)(b * NUM_MEM + m) * Dn + d) = a;
    }
}

// ---------------- Phase E: acc (B,M,D) -> out (B,C,H,W) ---------------------
__global__ __launch_bounds__(256) void k_q2x(const float* __restrict__ acc,
                                             float* __restrict__ out) {
    const int h = blockIdx.x;          // 0..47
    const int b = blockIdx.y;          // 0..7
    const int gh = h >> 4, i = h & 15;
    __shared__ float tile[Cn * Hn];    // [c][w]
    for (int gw = 0; gw < 3; ++gw) {
        const float* ap = acc + (size_t)(b * NUM_MEM + gh * 3 + gw) * Dn + i * (WSZ * Cn);
        for (int l = threadIdx.x; l < WSZ * Cn; l += blockDim.x) {
            int j = l >> 8, c = l & 255;
            tile[c * Hn + gw * WSZ + j] = ap[l];
        }
    }
    __syncthreads();
    float* op = out + (size_t)b * Cn * Hn * Hn + (size_t)h * Hn;
    for (int o = threadIdx.x; o < Cn * Hn; o += blockDim.x) {
        int c = o / Hn, wcol = o - c * Hn;
        op[(size_t)c * Hn * Hn + wcol] = tile[o];
    }
}

extern "C" void kernel_launch(void* const* d_in, const int* in_sizes, int n_in,
                              void* d_out, int out_size, void* d_ws, size_t ws_size,
                              hipStream_t stream) {
    const float* x    = (const float*)d_in[0];
    const float* mem1 = (const float*)d_in[1];
    const float* mem2 = (const float*)d_in[2];
    float* out = (float*)d_out;

    // workspace: q/acc [B*M*D floats], w [2*B*M*S floats]
    float* q    = (float*)d_ws;
    float* wbuf = q + (size_t)Bn * NUM_MEM * Dn;
    // att partials live in d_out (1.5 MB of its 18.9 MB) — k_q2x overwrites all later
    float* ap   = (float*)d_out;

    k_x2q<<<dim3(Hn, Bn), 256, 0, stream>>>(x, q);
    k_att3<<<dim3(ND2, NUM_MEM, 16), 256, 0, stream>>>(q, mem1, mem2, ap);
    k_smax<<<2 * Bn * NUM_MEM, 128, 0, stream>>>(ap, wbuf);
    k_acc<<<dim3(16, NUM_MEM, Bn), 256, 0, stream>>>(wbuf, mem1, mem2, q /*acc*/);
    k_q2x<<<dim3(Hn, Bn), 256, 0, stream>>>(q, out);
}

// Round 4
// 224.530 us; speedup vs baseline: 1.3973x; 1.0406x over previous
//
#include <hip/hip_runtime.h>
#include <hip/hip_bf16.h>
#include <cstdint>

// Problem dims
#define Bn 8
#define Cn 256
#define Hn 48
#define NUM_MEM 9
#define WSZ 16
#define Sn 128
#define Dn 65536   // 16*16*256
#define KTOP 5
#define NDC 128    // d-chunks for k_att4 (512 floats each)

// ---------------- Phase A: x (B,C,H,W) -> q (B,M,D), D = (i*16+j)*256 + c ----
__global__ __launch_bounds__(256) void k_x2q(const float* __restrict__ x,
                                             float* __restrict__ q) {
    const int h = blockIdx.x;          // 0..47
    const int b = blockIdx.y;          // 0..7
    const int gh = h >> 4, i = h & 15;
    __shared__ float tile[Cn * Hn];    // [c][w], 48KB
    const float* xp = x + (size_t)b * Cn * Hn * Hn + (size_t)h * Hn;
    for (int o = threadIdx.x; o < Cn * Hn; o += blockDim.x) {
        int c = o / Hn, w = o - c * Hn;
        tile[o] = xp[(size_t)c * Hn * Hn + w];
    }
    __syncthreads();
    for (int gw = 0; gw < 3; ++gw) {
        float* qp = q + (size_t)(b * NUM_MEM + gh * 3 + gw) * Dn + i * (WSZ * Cn);
        for (int l = threadIdx.x; l < WSZ * Cn; l += blockDim.x) {
            int j = l >> 8, c = l & 255;
            qp[l] = tile[c * Hn + gw * WSZ + j];
        }
    }
}

// ---------------- Phase B: single-shot partial dots -------------------------
// block = (dc, m, sgrp); wave owns rows R = sgrp*16 + wave*4 + r of the 256
// (e,s) rows (e = sgrp>>3, s = (sgrp&7)*16 + wave*4 + r), d-range
// [dc*512, dc*512+512). Every load independent, issued once; no loops over
// memory -> no loop-carried vmcnt serialization. Overlap comes from block
// churn (18432 blocks, ~4 waves/SIMD resident).
// ap[dc][(e*8+b)*9+m][s] = partial dot over the 512-float chunk.
__global__ __launch_bounds__(256) void k_att4(const float* __restrict__ q,
                                              const float* __restrict__ mem1,
                                              const float* __restrict__ mem2,
                                              float* __restrict__ ap) {
    const int dc = blockIdx.x;     // 0..127
    const int mw = blockIdx.y;     // 0..8
    const int sg = blockIdx.z;     // 0..15
    const int e  = sg >> 3;
    const int lane = threadIdx.x & 63, wave = threadIdx.x >> 6;
    const int s0 = (sg & 7) * 16 + wave * 4;        // first of 4 s-rows

    const float4* mem4 = (const float4*)(e ? mem2 : mem1);
    const float4* q4   = (const float4*)q;
    const int off = dc * 128 + lane;                // float4 offset of slice 0

    // 8 independent mem loads (4 rows x 2 slices), all issued up-front
    float4 M[4][2];
#pragma unroll
    for (int r = 0; r < 4; ++r) {
        const float4* mp = mem4 + (size_t)(mw * Sn + s0 + r) * (Dn / 4) + off;
        M[r][0] = mp[0];
        M[r][1] = mp[64];
    }

    float a[32];                                    // a[r*8+b]
#pragma unroll
    for (int i = 0; i < 32; ++i) a[i] = 0.f;

    // q in two b-halves to cap register pressure (~115 VGPR total)
#pragma unroll
    for (int half = 0; half < 2; ++half) {
        float4 Q[4][2];
#pragma unroll
        for (int b = 0; b < 4; ++b) {
            const float4* qp = q4 + (size_t)((half * 4 + b) * NUM_MEM + mw) * (Dn / 4) + off;
            Q[b][0] = qp[0];
            Q[b][1] = qp[64];
        }
#pragma unroll
        for (int r = 0; r < 4; ++r)
#pragma unroll
            for (int b = 0; b < 4; ++b) {
                const int bi = half * 4 + b;
                a[r * 8 + bi] += M[r][0].x * Q[b][0].x + M[r][0].y * Q[b][0].y
                               + M[r][0].z * Q[b][0].z + M[r][0].w * Q[b][0].w
                               + M[r][1].x * Q[b][1].x + M[r][1].y * Q[b][1].y
                               + M[r][1].z * Q[b][1].z + M[r][1].w * Q[b][1].w;
            }
    }

    // fold-reduce: 32 values across 64 lanes (verified in round 3)
#pragma unroll
    for (int k = 0; k < 5; ++k) {
        const int mk = 1 << k;
        const bool up = (lane & mk) != 0;
#pragma unroll
        for (int j = 0; j < (32 >> (k + 1)); ++j) {
            float lo = a[2 * j], hi = a[2 * j + 1];
            float mine = up ? hi : lo;
            float oth  = __shfl_xor(up ? lo : hi, mk, 64);
            a[j] = mine + oth;
        }
    }
    float rsum = a[0] + __shfl_xor(a[0], 32, 64);
    if (lane < 32) {
        const int b = lane & 7, r = (lane >> 3) & 3;
        ap[((size_t)dc * 144 + (size_t)(e * 8 + b) * 9 + mw) * Sn + (s0 + r)] = rsum;
    }
}

// ---------------- Phase C: nd-reduce + softmax + top-5 + shrink + L1 --------
__global__ __launch_bounds__(128) void k_smax(const float* __restrict__ ap,
                                              float* __restrict__ w) {
    const int row = blockIdx.x;        // 0..143  = (e*8+b)*9+m
    const int t = threadIdx.x;         // 0..127
    __shared__ float sf[Sn];
    __shared__ unsigned long long sk[Sn];

    float v = 0.f;
#pragma unroll 8
    for (int nd = 0; nd < NDC; ++nd)
        v += ap[((size_t)nd * 144 + row) * Sn + t];

    sf[t] = v; __syncthreads();
    for (int s = 64; s > 0; s >>= 1) { if (t < s) sf[t] = fmaxf(sf[t], sf[t + s]); __syncthreads(); }
    float mx = sf[0]; __syncthreads();

    float e = expf(v - mx);
    sf[t] = e; __syncthreads();
    for (int s = 64; s > 0; s >>= 1) { if (t < s) sf[t] += sf[t + s]; __syncthreads(); }
    float sum = sf[0]; __syncthreads();
    float y = e / sum;                 // softmax (y > 0)

    // 5 iterations of packed (value,index) argmax-with-exclusion -> 5th largest
    bool alive = true;
    float thres = 0.f;
    unsigned int ybits = __float_as_uint(y);   // y>0 -> bits monotonic
    for (int it = 0; it < KTOP; ++it) {
        sk[t] = alive ? ((((unsigned long long)ybits) << 32) | (unsigned)t) : 0ull;
        __syncthreads();
        for (int s = 64; s > 0; s >>= 1) {
            if (t < s) { if (sk[t + s] > sk[t]) sk[t] = sk[t + s]; }
            __syncthreads();
        }
        unsigned long long kmax = sk[0];
        __syncthreads();
        if ((unsigned)(kmax & 0xffffffffull) == (unsigned)t) alive = false;
        thres = __uint_as_float((unsigned)(kmax >> 32));
    }

    float d   = y - thres;
    float num = fmaxf(d, 0.f) * y;
    float yh  = num / (fabsf(d) + 1e-12f);     // exact reference formula

    sf[t] = yh; __syncthreads();
    for (int s = 64; s > 0; s >>= 1) { if (t < s) sf[t] += sf[t + s]; __syncthreads(); }
    float l1 = sf[0];
    w[(size_t)row * Sn + t] = yh / fmaxf(l1, 1e-12f);
}

// ---------------- Phase D: acc[b,m,:] = sum_s w1*mem1 + w2*mem2 -------------
__global__ __launch_bounds__(256) void k_acc(const float* __restrict__ w,
                                             const float* __restrict__ mem1,
                                             const float* __restrict__ mem2,
                                             float* __restrict__ acc) {
    const int chunk = blockIdx.x;      // 0..15 (4096 floats each)
    const int m     = blockIdx.y;      // 0..8
    const int b     = blockIdx.z;      // 0..7
    __shared__ int   nz[2];
    __shared__ int   idx[2][16];
    __shared__ float wv[2][16];
    if (threadIdx.x < 2) nz[threadIdx.x] = 0;
    __syncthreads();
    {
        int eidx = threadIdx.x >> 7;           // 0 or 1
        int s    = threadIdx.x & 127;
        float ww = w[((size_t)(eidx * Bn + b) * NUM_MEM + m) * Sn + s];
        if (ww != 0.f) {
            int p = atomicAdd(&nz[eidx], 1);
            if (p < 16) { idx[eidx][p] = s; wv[eidx][p] = ww; }
        }
    }
    __syncthreads();
    const int n1 = nz[0], n2 = nz[1];
    const size_t mbase = (size_t)m * Sn * Dn;
    const int dbase = chunk * 4096;
    for (int l = threadIdx.x * 4; l < 4096; l += 1024) {
        int d = dbase + l;
        float4 a = {0.f, 0.f, 0.f, 0.f};
        for (int j = 0; j < n1; ++j) {
            const float4 r = *(const float4*)(mem1 + mbase + (size_t)idx[0][j] * Dn + d);
            float ww = wv[0][j];
            a.x += ww * r.x; a.y += ww * r.y; a.z += ww * r.z; a.w += ww * r.w;
        }
        for (int j = 0; j < n2; ++j) {
            const float4 r = *(const float4*)(mem2 + mbase + (size_t)idx[1][j] * Dn + d);
            float ww = wv[1][j];
            a.x += ww * r.x; a.y += ww * r.y; a.z += ww * r.z; a.w += ww * r.w;
        }
        *(float4*)(acc + (size_t)(b * NUM_MEM + m) * Dn + d) = a;
    }
}

// ---------------- Phase E: acc (B,M,D) -> out (B,C,H,W) ---------------------
__global__ __launch_bounds__(256) void k_q2x(const float* __restrict__ acc,
                                             float* __restrict__ out) {
    const int h = blockIdx.x;          // 0..47
    const int b = blockIdx.y;          // 0..7
    const int gh = h >> 4, i = h & 15;
    __shared__ float tile[Cn * Hn];    // [c][w]
    for (int gw = 0; gw < 3; ++gw) {
        const float* ap = acc + (size_t)(b * NUM_MEM + gh * 3 + gw) * Dn + i * (WSZ * Cn);
        for (int l = threadIdx.x; l < WSZ * Cn; l += blockDim.x) {
            int j = l >> 8, c = l & 255;
            tile[c * Hn + gw * WSZ + j] = ap[l];
        }
    }
    __syncthreads();
    float* op = out + (size_t)b * Cn * Hn * Hn + (size_t)h * Hn;
    for (int o = threadIdx.x; o < Cn * Hn; o += blockDim.x) {
        int c = o / Hn, wcol = o - c * Hn;
        op[(size_t)c * Hn * Hn + wcol] = tile[o];
    }
}

extern "C" void kernel_launch(void* const* d_in, const int* in_sizes, int n_in,
                              void* d_out, int out_size, void* d_ws, size_t ws_size,
                              hipStream_t stream) {
    const float* x    = (const float*)d_in[0];
    const float* mem1 = (const float*)d_in[1];
    const float* mem2 = (const float*)d_in[2];
    float* out = (float*)d_out;

    // workspace: q/acc [B*M*D floats], w [2*B*M*S floats]
    float* q    = (float*)d_ws;
    float* wbuf = q + (size_t)Bn * NUM_MEM * Dn;
    // att partials live in d_out (9.4 MB of its 18.9 MB) — k_q2x overwrites all later
    float* ap   = (float*)d_out;

    k_x2q<<<dim3(Hn, Bn), 256, 0, stream>>>(x, q);
    k_att4<<<dim3(NDC, NUM_MEM, 16), 256, 0, stream>>>(q, mem1, mem2, ap);
    k_smax<<<2 * Bn * NUM_MEM, 128, 0, stream>>>(ap, wbuf);
    k_acc<<<dim3(16, NUM_MEM, Bn), 256, 0, stream>>>(wbuf, mem1, mem2, q /*acc*/);
    k_q2x<<<dim3(Hn, Bn), 256, 0, stream>>>(q, out);
}

// Round 6
// 220.280 us; speedup vs baseline: 1.4242x; 1.0193x over previous
//
#include <hip/hip_runtime.h>
#include <hip/hip_bf16.h>
#include <cstdint>

// Problem dims
#define Bn 8
#define Cn 256
#define Hn 48
#define NUM_MEM 9
#define WSZ 16
#define Sn 128
#define Dn 65536   // 16*16*256
#define KTOP 5
#define NDC 128    // d-chunks (512 floats each)
#define TW 512     // floats per d-chunk

typedef const __attribute__((address_space(1))) uint32_t* gptr_t;
typedef __attribute__((address_space(3))) uint32_t* lptr_t;

// ---------------- Phase A: x (B,C,H,W) -> q (B,M,D), D = (i*16+j)*256 + c ----
__global__ __launch_bounds__(256) void k_x2q(const float* __restrict__ x,
                                             float* __restrict__ q) {
    const int h = blockIdx.x;          // 0..47
    const int b = blockIdx.y;          // 0..7
    const int gh = h >> 4, i = h & 15;
    __shared__ float tile[Cn * Hn];    // [c][w], 48KB
    const float* xp = x + (size_t)b * Cn * Hn * Hn + (size_t)h * Hn;
    for (int o = threadIdx.x; o < Cn * Hn; o += blockDim.x) {
        int c = o / Hn, w = o - c * Hn;
        tile[o] = xp[(size_t)c * Hn * Hn + w];
    }
    __syncthreads();
    for (int gw = 0; gw < 3; ++gw) {
        float* qp = q + (size_t)(b * NUM_MEM + gh * 3 + gw) * Dn + i * (WSZ * Cn);
        for (int l = threadIdx.x; l < WSZ * Cn; l += blockDim.x) {
            int j = l >> 8, c = l & 255;
            qp[l] = tile[c * Hn + gw * WSZ + j];
        }
    }
}

// ---------------- Phase B: global_load_lds staged partial dots ---------------
// block = (dc, m, e); 8 tiles of 16 s-rows; wave w owns rows t*16 + w*4 + r.
// Each wave stages ITS OWN rows (8 x 1KB width-16 global_load_lds per tile)
// into a private LDS region, double-buffered, counted vmcnt(8) -> next tile's
// loads stay in flight during compute. No barriers; waves fully independent.
// ap[dc][(e*8+b)*9+m][s] = partial dot over [dc*512, dc*512+512).
__global__ __launch_bounds__(256) void k_att5(const float* __restrict__ q,
                                              const float* __restrict__ mem1,
                                              const float* __restrict__ mem2,
                                              float* __restrict__ ap) {
    const int dc = blockIdx.x;     // 0..127
    const int mw = blockIdx.y;     // 0..8
    const int e  = blockIdx.z;     // 0..1
    const int lane = threadIdx.x & 63, wave = threadIdx.x >> 6;

    const float* mem = e ? mem2 : mem1;
    const float4* q4 = (const float4*)q;

    __shared__ float lds[4][2][4][TW];   // [wave][buf][row][floats] = 64 KB

    // register-cache q chunk: 8 batches x 2 float4 per lane
    float4 Q[8][2];
#pragma unroll
    for (int b = 0; b < 8; ++b) {
        const size_t qb = (size_t)(b * NUM_MEM + mw) * (Dn / 4) + (size_t)dc * (TW / 4);
        Q[b][0] = q4[qb + lane];
        Q[b][1] = q4[qb + 64 + lane];
    }

    // stage tile t into buf: 8 width-16 loads (4 rows x 2 halves)
    auto stage = [&](int t, int buf) {
#pragma unroll
        for (int u = 0; u < 8; ++u) {
            const int r = u >> 1, half = u & 1;
            const float* src = mem + ((size_t)(mw * Sn + t * 16 + wave * 4 + r)) * Dn
                             + (size_t)dc * TW + half * 256 + lane * 4;
            __builtin_amdgcn_global_load_lds((gptr_t)src,
                                             (lptr_t)&lds[wave][buf][r][half * 256],
                                             16, 0, 0);
        }
    };

    stage(0, 0);

    for (int t = 0; t < 8; ++t) {
        const int buf = t & 1;
        if (t < 7) stage(t + 1, buf ^ 1);

        if (t < 7) { asm volatile("s_waitcnt vmcnt(8)" ::: "memory"); }
        else       { asm volatile("s_waitcnt vmcnt(0)" ::: "memory"); }
        __builtin_amdgcn_sched_barrier(0);

        float a[32];                       // a[r*8+b]
#pragma unroll
        for (int r = 0; r < 4; ++r) {
            float4 m0 = *(const float4*)&lds[wave][buf][r][lane * 4];
            float4 m1 = *(const float4*)&lds[wave][buf][r][256 + lane * 4];  // FIXED: 256 floats, not 1024
#pragma unroll
            for (int b = 0; b < 8; ++b) {
                a[r * 8 + b] = m0.x * Q[b][0].x + m0.y * Q[b][0].y
                             + m0.z * Q[b][0].z + m0.w * Q[b][0].w
                             + m1.x * Q[b][1].x + m1.y * Q[b][1].y
                             + m1.z * Q[b][1].z + m1.w * Q[b][1].w;
            }
        }

        // fold-reduce: 32 values across 64 lanes (verified rounds 3-4)
#pragma unroll
        for (int k = 0; k < 5; ++k) {
            const int mk = 1 << k;
            const bool up = (lane & mk) != 0;
#pragma unroll
            for (int j = 0; j < (32 >> (k + 1)); ++j) {
                float lo = a[2 * j], hi = a[2 * j + 1];
                float mine = up ? hi : lo;
                float oth  = __shfl_xor(up ? lo : hi, mk, 64);
                a[j] = mine + oth;
            }
        }
        float rsum = a[0] + __shfl_xor(a[0], 32, 64);
        if (lane < 32) {
            const int b = lane & 7, r = (lane >> 3) & 3;
            const int s = t * 16 + wave * 4 + r;
            ap[((size_t)dc * 144 + (size_t)(e * 8 + b) * 9 + mw) * Sn + s] = rsum;
        }
    }
}

// ---------------- Phase C: nd-reduce + softmax + top-5 + shrink + L1 --------
__global__ __launch_bounds__(128) void k_smax(const float* __restrict__ ap,
                                              float* __restrict__ w) {
    const int row = blockIdx.x;        // 0..143  = (e*8+b)*9+m
    const int t = threadIdx.x;         // 0..127
    __shared__ float sf[Sn];
    __shared__ unsigned long long sk[Sn];

    float v = 0.f;
#pragma unroll 8
    for (int nd = 0; nd < NDC; ++nd)
        v += ap[((size_t)nd * 144 + row) * Sn + t];

    sf[t] = v; __syncthreads();
    for (int s = 64; s > 0; s >>= 1) { if (t < s) sf[t] = fmaxf(sf[t], sf[t + s]); __syncthreads(); }
    float mx = sf[0]; __syncthreads();

    float e = expf(v - mx);
    sf[t] = e; __syncthreads();
    for (int s = 64; s > 0; s >>= 1) { if (t < s) sf[t] += sf[t + s]; __syncthreads(); }
    float sum = sf[0]; __syncthreads();
    float y = e / sum;                 // softmax (y > 0)

    // 5 iterations of packed (value,index) argmax-with-exclusion -> 5th largest
    bool alive = true;
    float thres = 0.f;
    unsigned int ybits = __float_as_uint(y);   // y>0 -> bits monotonic
    for (int it = 0; it < KTOP; ++it) {
        sk[t] = alive ? ((((unsigned long long)ybits) << 32) | (unsigned)t) : 0ull;
        __syncthreads();
        for (int s = 64; s > 0; s >>= 1) {
            if (t < s) { if (sk[t + s] > sk[t]) sk[t] = sk[t + s]; }
            __syncthreads();
        }
        unsigned long long kmax = sk[0];
        __syncthreads();
        if ((unsigned)(kmax & 0xffffffffull) == (unsigned)t) alive = false;
        thres = __uint_as_float((unsigned)(kmax >> 32));
    }

    float d   = y - thres;
    float num = fmaxf(d, 0.f) * y;
    float yh  = num / (fabsf(d) + 1e-12f);     // exact reference formula

    sf[t] = yh; __syncthreads();
    for (int s = 64; s > 0; s >>= 1) { if (t < s) sf[t] += sf[t + s]; __syncthreads(); }
    float l1 = sf[0];
    w[(size_t)row * Sn + t] = yh / fmaxf(l1, 1e-12f);
}

// ---------------- Phase D: acc[b,m,:] = sum_s w1*mem1 + w2*mem2 -------------
__global__ __launch_bounds__(256) void k_acc(const float* __restrict__ w,
                                             const float* __restrict__ mem1,
                                             const float* __restrict__ mem2,
                                             float* __restrict__ acc) {
    const int chunk = blockIdx.x;      // 0..15 (4096 floats each)
    const int m     = blockIdx.y;      // 0..8
    const int b     = blockIdx.z;      // 0..7
    __shared__ int   nz[2];
    __shared__ int   idx[2][16];
    __shared__ float wv[2][16];
    if (threadIdx.x < 2) nz[threadIdx.x] = 0;
    __syncthreads();
    {
        int eidx = threadIdx.x >> 7;           // 0 or 1
        int s    = threadIdx.x & 127;
        float ww = w[((size_t)(eidx * Bn + b) * NUM_MEM + m) * Sn + s];
        if (ww != 0.f) {
            int p = atomicAdd(&nz[eidx], 1);
            if (p < 16) { idx[eidx][p] = s; wv[eidx][p] = ww; }
        }
    }
    __syncthreads();
    const int n1 = nz[0], n2 = nz[1];
    const size_t mbase = (size_t)m * Sn * Dn;
    const int dbase = chunk * 4096;
    for (int l = threadIdx.x * 4; l < 4096; l += 1024) {
        int d = dbase + l;
        float4 a = {0.f, 0.f, 0.f, 0.f};
        for (int j = 0; j < n1; ++j) {
            const float4 r = *(const float4*)(mem1 + mbase + (size_t)idx[0][j] * Dn + d);
            float ww = wv[0][j];
            a.x += ww * r.x; a.y += ww * r.y; a.z += ww * r.z; a.w += ww * r.w;
        }
        for (int j = 0; j < n2; ++j) {
            const float4 r = *(const float4*)(mem2 + mbase + (size_t)idx[1][j] * Dn + d);
            float ww = wv[1][j];
            a.x += ww * r.x; a.y += ww * r.y; a.z += ww * r.z; a.w += ww * r.w;
        }
        *(float4*)(acc + (size_t)(b * NUM_MEM + m) * Dn + d) = a;
    }
}

// ---------------- Phase E: acc (B,M,D) -> out (B,C,H,W) ---------------------
__global__ __launch_bounds__(256) void k_q2x(const float* __restrict__ acc,
                                             float* __restrict__ out) {
    const int h = blockIdx.x;          // 0..47
    const int b = blockIdx.y;          // 0..7
    const int gh = h >> 4, i = h & 15;
    __shared__ float tile[Cn * Hn];    // [c][w]
    for (int gw = 0; gw < 3; ++gw) {
        const float* ap = acc + (size_t)(b * NUM_MEM + gh * 3 + gw) * Dn + i * (WSZ * Cn);
        for (int l = threadIdx.x; l < WSZ * Cn; l += blockDim.x) {
            int j = l >> 8, c = l & 255;
            tile[c * Hn + gw * WSZ + j] = ap[l];
        }
    }
    __syncthreads();
    float* op = out + (size_t)b * Cn * Hn * Hn + (size_t)h * Hn;
    for (int o = threadIdx.x; o < Cn * Hn; o += blockDim.x) {
        int c = o / Hn, wcol = o - c * Hn;
        op[(size_t)c * Hn * Hn + wcol] = tile[o];
    }
}

extern "C" void kernel_launch(void* const* d_in, const int* in_sizes, int n_in,
                              void* d_out, int out_size, void* d_ws, size_t ws_size,
                              hipStream_t stream) {
    const float* x    = (const float*)d_in[0];
    const float* mem1 = (const float*)d_in[1];
    const float* mem2 = (const float*)d_in[2];
    float* out = (float*)d_out;

    // workspace: q/acc [B*M*D floats], w [2*B*M*S floats]
    float* q    = (float*)d_ws;
    float* wbuf = q + (size_t)Bn * NUM_MEM * Dn;
    // att partials live in d_out (9.4 MB of its 18.9 MB) — k_q2x overwrites all later
    float* ap   = (float*)d_out;

    k_x2q<<<dim3(Hn, Bn), 256, 0, stream>>>(x, q);
    k_att5<<<dim3(NDC, NUM_MEM, 2), 256, 0, stream>>>(q, mem1, mem2, ap);
    k_smax<<<2 * Bn * NUM_MEM, 128, 0, stream>>>(ap, wbuf);
    k_acc<<<dim3(16, NUM_MEM, Bn), 256, 0, stream>>>(wbuf, mem1, mem2, q /*acc*/);
    k_q2x<<<dim3(Hn, Bn), 256, 0, stream>>>(q, out);
}

// Round 7
// 198.452 us; speedup vs baseline: 1.5809x; 1.1100x over previous
//
#include <hip/hip_runtime.h>
#include <hip/hip_bf16.h>
#include <cstdint>

// Problem dims
#define Bn 8
#define Cn 256
#define Hn 48
#define NUM_MEM 9
#define WSZ 16
#define Sn 128
#define Dn 65536   // 16*16*256
#define KTOP 5
#define NDC 128    // d-chunks (512 floats each)

typedef float f32x4 __attribute__((ext_vector_type(4)));

// ---------------- Phase A: x (B,C,H,W) -> q (B,M,D), D = (i*16+j)*256 + c ----
__global__ __launch_bounds__(256) void k_x2q(const float* __restrict__ x,
                                             float* __restrict__ q) {
    const int h = blockIdx.x;          // 0..47
    const int b = blockIdx.y;          // 0..7
    const int gh = h >> 4, i = h & 15;
    __shared__ float tile[Cn * Hn];    // [c][w], 48KB
    const float* xp = x + (size_t)b * Cn * Hn * Hn + (size_t)h * Hn;
    for (int o = threadIdx.x; o < Cn * Hn; o += blockDim.x) {
        int c = o / Hn, w = o - c * Hn;
        tile[o] = xp[(size_t)c * Hn * Hn + w];
    }
    __syncthreads();
    for (int gw = 0; gw < 3; ++gw) {
        float* qp = q + (size_t)(b * NUM_MEM + gh * 3 + gw) * Dn + i * (WSZ * Cn);
        for (int l = threadIdx.x; l < WSZ * Cn; l += blockDim.x) {
            int j = l >> 8, c = l & 255;
            qp[l] = tile[c * Hn + gw * WSZ + j];
        }
    }
}

// ---------------- Phase B: single-shot partial dots, NON-TEMPORAL mem reads --
// Identical structure to round-4 k_att4 (passed, tied-fastest). One variable
// changed: mem loads use __builtin_nontemporal_load (nt flag) to bypass
// L2/L3 caching -> no Infinity-Cache fill/evict churn on the 604 MB stream.
// q loads stay cached (real L2 reuse across sgrp-sibling blocks).
// ap[dc][(e*8+b)*9+m][s] = partial dot over the 512-float chunk.
__global__ __launch_bounds__(256) void k_att6(const float* __restrict__ q,
                                              const float* __restrict__ mem1,
                                              const float* __restrict__ mem2,
                                              float* __restrict__ ap) {
    const int dc = blockIdx.x;     // 0..127
    const int mw = blockIdx.y;     // 0..8
    const int sg = blockIdx.z;     // 0..15
    const int e  = sg >> 3;
    const int lane = threadIdx.x & 63, wave = threadIdx.x >> 6;
    const int s0 = (sg & 7) * 16 + wave * 4;        // first of 4 s-rows

    const f32x4* mem4 = (const f32x4*)(e ? mem2 : mem1);
    const f32x4* q4   = (const f32x4*)q;
    const int off = dc * 128 + lane;                // f32x4 offset of slice 0

    // 8 independent non-temporal mem loads (4 rows x 2 slices), issued up-front
    f32x4 M[4][2];
#pragma unroll
    for (int r = 0; r < 4; ++r) {
        const f32x4* mp = mem4 + (size_t)(mw * Sn + s0 + r) * (Dn / 4) + off;
        M[r][0] = __builtin_nontemporal_load(mp);
        M[r][1] = __builtin_nontemporal_load(mp + 64);
    }

    float a[32];                                    // a[r*8+b]
#pragma unroll
    for (int i = 0; i < 32; ++i) a[i] = 0.f;

    // q in two b-halves to cap register pressure
#pragma unroll
    for (int half = 0; half < 2; ++half) {
        f32x4 Q[4][2];
#pragma unroll
        for (int b = 0; b < 4; ++b) {
            const f32x4* qp = q4 + (size_t)((half * 4 + b) * NUM_MEM + mw) * (Dn / 4) + off;
            Q[b][0] = qp[0];
            Q[b][1] = qp[64];
        }
#pragma unroll
        for (int r = 0; r < 4; ++r)
#pragma unroll
            for (int b = 0; b < 4; ++b) {
                const int bi = half * 4 + b;
                float acc = a[r * 8 + bi];
#pragma unroll
                for (int k = 0; k < 4; ++k)
                    acc += M[r][0][k] * Q[b][0][k] + M[r][1][k] * Q[b][1][k];
                a[r * 8 + bi] = acc;
            }
    }

    // fold-reduce: 32 values across 64 lanes (verified rounds 3-6)
#pragma unroll
    for (int k = 0; k < 5; ++k) {
        const int mk = 1 << k;
        const bool up = (lane & mk) != 0;
#pragma unroll
        for (int j = 0; j < (32 >> (k + 1)); ++j) {
            float lo = a[2 * j], hi = a[2 * j + 1];
            float mine = up ? hi : lo;
            float oth  = __shfl_xor(up ? lo : hi, mk, 64);
            a[j] = mine + oth;
        }
    }
    float rsum = a[0] + __shfl_xor(a[0], 32, 64);
    if (lane < 32) {
        const int b = lane & 7, r = (lane >> 3) & 3;
        ap[((size_t)dc * 144 + (size_t)(e * 8 + b) * 9 + mw) * Sn + (s0 + r)] = rsum;
    }
}

// ---------------- Phase C: nd-reduce + softmax + top-5 + shrink + L1 --------
__global__ __launch_bounds__(128) void k_smax(const float* __restrict__ ap,
                                              float* __restrict__ w) {
    const int row = blockIdx.x;        // 0..143  = (e*8+b)*9+m
    const int t = threadIdx.x;         // 0..127
    __shared__ float sf[Sn];
    __shared__ unsigned long long sk[Sn];

    float v = 0.f;
#pragma unroll 8
    for (int nd = 0; nd < NDC; ++nd)
        v += ap[((size_t)nd * 144 + row) * Sn + t];

    sf[t] = v; __syncthreads();
    for (int s = 64; s > 0; s >>= 1) { if (t < s) sf[t] = fmaxf(sf[t], sf[t + s]); __syncthreads(); }
    float mx = sf[0]; __syncthreads();

    float e = expf(v - mx);
    sf[t] = e; __syncthreads();
    for (int s = 64; s > 0; s >>= 1) { if (t < s) sf[t] += sf[t + s]; __syncthreads(); }
    float sum = sf[0]; __syncthreads();
    float y = e / sum;                 // softmax (y > 0)

    // 5 iterations of packed (value,index) argmax-with-exclusion -> 5th largest
    bool alive = true;
    float thres = 0.f;
    unsigned int ybits = __float_as_uint(y);   // y>0 -> bits monotonic
    for (int it = 0; it < KTOP; ++it) {
        sk[t] = alive ? ((((unsigned long long)ybits) << 32) | (unsigned)t) : 0ull;
        __syncthreads();
        for (int s = 64; s > 0; s >>= 1) {
            if (t < s) { if (sk[t + s] > sk[t]) sk[t] = sk[t + s]; }
            __syncthreads();
        }
        unsigned long long kmax = sk[0];
        __syncthreads();
        if ((unsigned)(kmax & 0xffffffffull) == (unsigned)t) alive = false;
        thres = __uint_as_float((unsigned)(kmax >> 32));
    }

    float d   = y - thres;
    float num = fmaxf(d, 0.f) * y;
    float yh  = num / (fabsf(d) + 1e-12f);     // exact reference formula

    sf[t] = yh; __syncthreads();
    for (int s = 64; s > 0; s >>= 1) { if (t < s) sf[t] += sf[t + s]; __syncthreads(); }
    float l1 = sf[0];
    w[(size_t)row * Sn + t] = yh / fmaxf(l1, 1e-12f);
}

// ---------------- Phase D: acc[b,m,:] = sum_s w1*mem1 + w2*mem2 -------------
__global__ __launch_bounds__(256) void k_acc(const float* __restrict__ w,
                                             const float* __restrict__ mem1,
                                             const float* __restrict__ mem2,
                                             float* __restrict__ acc) {
    const int chunk = blockIdx.x;      // 0..15 (4096 floats each)
    const int m     = blockIdx.y;      // 0..8
    const int b     = blockIdx.z;      // 0..7
    __shared__ int   nz[2];
    __shared__ int   idx[2][16];
    __shared__ float wv[2][16];
    if (threadIdx.x < 2) nz[threadIdx.x] = 0;
    __syncthreads();
    {
        int eidx = threadIdx.x >> 7;           // 0 or 1
        int s    = threadIdx.x & 127;
        float ww = w[((size_t)(eidx * Bn + b) * NUM_MEM + m) * Sn + s];
        if (ww != 0.f) {
            int p = atomicAdd(&nz[eidx], 1);
            if (p < 16) { idx[eidx][p] = s; wv[eidx][p] = ww; }
        }
    }
    __syncthreads();
    const int n1 = nz[0], n2 = nz[1];
    const size_t mbase = (size_t)m * Sn * Dn;
    const int dbase = chunk * 4096;
    for (int l = threadIdx.x * 4; l < 4096; l += 1024) {
        int d = dbase + l;
        float4 a = {0.f, 0.f, 0.f, 0.f};
        for (int j = 0; j < n1; ++j) {
            const float4 r = *(const float4*)(mem1 + mbase + (size_t)idx[0][j] * Dn + d);
            float ww = wv[0][j];
            a.x += ww * r.x; a.y += ww * r.y; a.z += ww * r.z; a.w += ww * r.w;
        }
        for (int j = 0; j < n2; ++j) {
            const float4 r = *(const float4*)(mem2 + mbase + (size_t)idx[1][j] * Dn + d);
            float ww = wv[1][j];
            a.x += ww * r.x; a.y += ww * r.y; a.z += ww * r.z; a.w += ww * r.w;
        }
        *(float4*)(acc + (size_t)(b * NUM_MEM + m) * Dn + d) = a;
    }
}

// ---------------- Phase E: acc (B,M,D) -> out (B,C,H,W) ---------------------
__global__ __launch_bounds__(256) void k_q2x(const float* __restrict__ acc,
                                             float* __restrict__ out) {
    const int h = blockIdx.x;          // 0..47
    const int b = blockIdx.y;          // 0..7
    const int gh = h >> 4, i = h & 15;
    __shared__ float tile[Cn * Hn];    // [c][w]
    for (int gw = 0; gw < 3; ++gw) {
        const float* ap = acc + (size_t)(b * NUM_MEM + gh * 3 + gw) * Dn + i * (WSZ * Cn);
        for (int l = threadIdx.x; l < WSZ * Cn; l += blockDim.x) {
            int j = l >> 8, c = l & 255;
            tile[c * Hn + gw * WSZ + j] = ap[l];
        }
    }
    __syncthreads();
    float* op = out + (size_t)b * Cn * Hn * Hn + (size_t)h * Hn;
    for (int o = threadIdx.x; o < Cn * Hn; o += blockDim.x) {
        int c = o / Hn, wcol = o - c * Hn;
        op[(size_t)c * Hn * Hn + wcol] = tile[o];
    }
}

extern "C" void kernel_launch(void* const* d_in, const int* in_sizes, int n_in,
                              void* d_out, int out_size, void* d_ws, size_t ws_size,
                              hipStream_t stream) {
    const float* x    = (const float*)d_in[0];
    const float* mem1 = (const float*)d_in[1];
    const float* mem2 = (const float*)d_in[2];
    float* out = (float*)d_out;

    // workspace: q/acc [B*M*D floats], w [2*B*M*S floats]
    float* q    = (float*)d_ws;
    float* wbuf = q + (size_t)Bn * NUM_MEM * Dn;
    // att partials live in d_out (9.4 MB of its 18.9 MB) — k_q2x overwrites all later
    float* ap   = (float*)d_out;

    k_x2q<<<dim3(Hn, Bn), 256, 0, stream>>>(x, q);
    k_att6<<<dim3(NDC, NUM_MEM, 16), 256, 0, stream>>>(q, mem1, mem2, ap);
    k_smax<<<2 * Bn * NUM_MEM, 128, 0, stream>>>(ap, wbuf);
    k_acc<<<dim3(16, NUM_MEM, Bn), 256, 0, stream>>>(wbuf, mem1, mem2, q /*acc*/);
    k_q2x<<<dim3(Hn, Bn), 256, 0, stream>>>(q, out);
}